// Round 2
// 2575.475 us; speedup vs baseline: 1.1207x; 1.1207x over previous
//
#include <hip/hip_runtime.h>
#include <math.h>

// ---------------- problem constants ----------------
#define HC 96
#define WC 96
#define CCH 64
#define BB 8
#define NL 8
#define IMG (HC*WC)                 // 9216
#define LSTRIDE (BB*CCH*IMG)        // 4,718,592
#define EPS 1e-5f

// padded-chunked NHWC bf16 layout: [b][ch2][y:98][x:98][ic:32]
#define PY 98
#define PX 98
#define ICH 32
#define PLANE (PY*PX*ICH)           // 307,328
#define PL (BB*2*PLANE)             // 4,917,248 els per layer tensor
#define APK_L (2*9*2*64*32)         // 73,728 els per layer per direction

typedef __bf16 bf16;
typedef bf16 bf16x8 __attribute__((ext_vector_type(8)));
typedef float f32x4 __attribute__((ext_vector_type(4)));

__device__ __forceinline__ float a_of(int i){ return sqrtf((i+1.f)/(i+2.f)); }
__device__ __forceinline__ float b_of(int i){ return sqrtf((float)i/(float)(i+1)); }

// ---------------------------------------------------------------------------
// Split weights into hi/lo bf16 planes, frag-friendly layout:
// apX[l][ch][tap][rep][oc64][ic32]. fwd: K[l][oc][ic][tap]; bwd: K[l][ic][oc][8-tap].
__global__ void pack_weights(const float* __restrict__ K,
                             bf16* __restrict__ apf, bf16* __restrict__ apb){
  int idx = blockIdx.x*256 + threadIdx.x;          // NL*9*64*64
  if (idx >= NL*9*64*64) return;
  int ic = idx & 63, oc = (idx>>6) & 63;
  int tap = (idx>>12) % 9, l = idx/(4096*9);
  float wf = K[(((size_t)l*64 + oc)*64 + ic)*9 + tap];
  float wb = K[(((size_t)l*64 + ic)*64 + oc)*9 + (8-tap)];
  int ch = ic>>5, ic5 = ic&31;
  size_t base = (size_t)l*APK_L + ((size_t)((ch*9 + tap)*2)*64 + oc)*32 + ic5;
  bf16 fh = (bf16)wf;
  apf[base] = fh; apf[base + 64*32] = (bf16)(wf - (float)fh);
  bf16 bh = (bf16)wb;
  apb[base] = bh; apb[base + 64*32] = (bf16)(wb - (float)bh);
}

// ---------------------------------------------------------------------------
// Fix-iter 0 constant-folded: Yf closed form from X, X0; writes padded NHWC bf16.
__global__ __launch_bounds__(256) void init_yf_t(const float* __restrict__ X,
                                                 const float* __restrict__ X0,
                                                 bf16* __restrict__ yfq){
  __shared__ float LX[64][97];
  __shared__ float L0[64][97];
  int b = blockIdx.y, y = blockIdx.x;
  for (int i = threadIdx.x; i < 64*96; i += 256){
    int c = i/96, x = i%96;
    LX[c][x] = X[(((size_t)b*64 + c)*96 + y)*96 + x];
    L0[c][x] = X0[((size_t)c*96 + y)*96 + x];
  }
  __syncthreads();
  for (int j = threadIdx.x; j < 96*64; j += 256){
    int x = j>>6, c = j&63;
    float xv = LX[c][x], x0v = L0[c][x];
    size_t eoff = ((size_t)(b*2 + (c>>5))*PY + (y+1))*(size_t)PX*ICH
                + (size_t)(x+1)*ICH + (c&31);
    float yf = 0.f;
#pragma unroll
    for (int i = 0; i < NL; i++){
      float yv = (i==0 ? x0v : 0.f) + (i==NL-1 ? xv : 0.f);
      yf = a_of(i)*(b_of(i)*yf + yv);
      yfq[(size_t)i*PL + eoff] = (bf16)yf;
    }
  }
}

// ---------------------------------------------------------------------------
// Backward scan in place over padded bf16 Yf->Z (pads are 0 and map to 0).
__global__ __launch_bounds__(256) void back_scan_q(bf16* __restrict__ buf){
  size_t base = ((size_t)blockIdx.x*256 + threadIdx.x)*8;
  float c[8];
#pragma unroll
  for (int e=0;e<8;e++) c[e]=0.f;
#pragma unroll
  for (int l = NL-1; l >= 0; l--){
    float al = a_of(l);
    uint4 v = *(const uint4*)(buf + (size_t)l*PL + base);
    bf16* h = (bf16*)&v;
    uint4 o; bf16* ho = (bf16*)&o;
#pragma unroll
    for (int e=0;e<8;e++){
      float z = al*(al*c[e] + (float)h[e]);
      ho[e] = (bf16)z; c[e] = z;
    }
    *(uint4*)(buf + (size_t)l*PL + base) = o;
  }
}

// Final backward scan: fp32 NCHW in zbase (d_out), emits out0 = Z[7].
__global__ __launch_bounds__(256) void back_scan_final(float* __restrict__ zbase,
                                                       float* __restrict__ out0){
  int idx = blockIdx.x*256 + threadIdx.x;
  float c = 0.f;
#pragma unroll
  for (int i = NL-1; i >= 0; i--){
    float ai = a_of(i);
    float z = ai*(ai*c + zbase[(size_t)i*LSTRIDE + idx]);
    zbase[(size_t)i*LSTRIDE + idx] = z;
    if (i == NL-1) out0[idx] = z;
    c = z;
  }
}

// ---------------------------------------------------------------------------
// Instance-norm stats over dZf (NHWC fp32): partial sums + device atomics.
__global__ __launch_bounds__(256) void stats_partial(const float* __restrict__ dZf,
                                                     float* __restrict__ acc){
  int b = blockIdx.y, slab = blockIdx.x;
  int oc = threadIdx.x & 63, pg = threadIdx.x >> 6;
  float s = 0.f, s2 = 0.f;
  for (int r = 0; r < 8; r++){
    int y = slab*8 + r;
    const float* row = dZf + (((size_t)b*96 + y)*96)*64;
    for (int xx = pg; xx < 96; xx += 4){
      float v = row[(size_t)xx*64 + oc];
      s += v; s2 += v*v;
    }
  }
  __shared__ float rs[256], rs2[256];
  rs[threadIdx.x] = s; rs2[threadIdx.x] = s2;
  __syncthreads();
  if (threadIdx.x < 64){
    s  = rs[oc] + rs[64+oc] + rs[128+oc] + rs[192+oc];
    s2 = rs2[oc] + rs2[64+oc] + rs2[128+oc] + rs2[192+oc];
    atomicAdd(&acc[(b*64 + oc)*2], s);
    atomicAdd(&acc[(b*64 + oc)*2 + 1], s2);
  }
}

__global__ void stat_fin(float* __restrict__ acc, float2* __restrict__ st){
  int bc = threadIdx.x;   // 512
  float s = acc[bc*2], s2 = acc[bc*2+1];
  float m = s*(1.f/IMG);
  float v = s2*(1.f/IMG) - m*m;
  if (v < 0.f) v = 0.f;
  st[bc] = make_float2(m, rsqrtf(v + EPS));
  acc[bc*2] = 0.f; acc[bc*2+1] = 0.f;   // re-zero for next layer-step
}

// ---------------------------------------------------------------------------
// Normalize + leaky-relu + quantize to padded NHWC bf16 (pads untouched/zero).
__global__ __launch_bounds__(256) void norm_cvt(const float* __restrict__ dZf,
                                                const float2* __restrict__ st,
                                                bf16* __restrict__ dzq){
  int i4 = blockIdx.x*256 + threadIdx.x;   // LSTRIDE/4
  size_t e = (size_t)i4*4;
  int oc = (int)(e & 63);
  size_t px = e >> 6;
  int x = (int)(px % 96); size_t t = px / 96;
  int y = (int)(t % 96);  int b = (int)(t / 96);
  const float* p = dZf + e;
  union { uint2 v; unsigned short u[4]; } o;
#pragma unroll
  for (int k=0;k<4;k++){
    float2 mr = st[b*64 + oc + k];
    float v = (p[k] - mr.x)*mr.y;
    v = (v >= 0.f) ? v : 0.2f*v;
    bf16 h = (bf16)v;
    o.u[k] = *(unsigned short*)&h;
  }
  size_t off = ((size_t)(b*2 + (oc>>5))*PY + (y+1))*(size_t)PX*ICH
             + (size_t)(x+1)*ICH + (oc&31);
  *(uint2*)(dzq + off) = o.v;
}

// ---------------------------------------------------------------------------
// MFMA implicit-GEMM 3x3 conv, pad=1, 2-pass split weights (Wh+Wl)*bf16(in).
// R1 changes vs previous session (resubmitted unchanged after infra failure):
//  * oc split across blockIdx.z (2 half-blocks of 32 oc) -> grid 768 = 3*256,
//    __launch_bounds__(256,3): perfectly balanced, 3 blocks/CU resident.
//  * XOR bank-swizzle on BOTH LDS operand buffers. Old pattern: lane address
//    stride 64B across the 16 lanes of a q-group -> addr bits[6:4] take only
//    2 of 8 values -> 4x bank conflict on every ds_read_b128. Swizzle:
//    16B-slot ^= (idx&3)^((idx>>2)&3), applied at stage AND read (bit-exact
//    involution) -> each q-group spreads over all 8 bank-quads (2-way = free).
// Block: 32 oc x (2 rows x 96 cols); wave = 2 M-tiles x 3 N-tiles.
// MODE 0: -> dZf (NHWC fp32, via LDS transpose)
// MODE 1: yv=-acc(+X/+X0); yf=a*(b*prev_q+yv) -> Yfq bf16 padded (transpose)
// MODE 2: same math fp32, direct NCHW stores to zbase (final iteration)
template<int MODE>
__global__ __launch_bounds__(256, 3) void conv_mfma(
    const bf16* __restrict__ inq, const bf16* __restrict__ apk,
    float* __restrict__ outF,
    bf16* __restrict__ yfq_out, const bf16* __restrict__ yfq_prev,
    float* __restrict__ zb_out, const float* __restrict__ zb_prev,
    const float* __restrict__ Xadd, const float* __restrict__ X0add,
    float a_i, float b_i)
{
  __shared__ __align__(16) char smem[25088 + 12288];
  char* Bbc = smem;                        // [4 rows][98 px][32 ic] bf16, swizzled
  char* Abc = smem + 25088;                // [3 taps][2 rep][32 oc][32 ic] bf16, swizzled

  const int rowg = blockIdx.x, b = blockIdx.y, h = blockIdx.z;  // h = oc half
  const int y0 = rowg*2;
  const int tid = threadIdx.x;
  const int w = tid>>6, lane = tid&63;
  const int n16 = lane&15, q = lane>>4;
  const int wr = w>>1, wcol = (w&1)*48;
  const int yg = y0 + wr;

  f32x4 acc[2][3];
#pragma unroll
  for (int a=0;a<2;a++)
#pragma unroll
    for (int c=0;c<3;c++){ f32x4 z = {0.f,0.f,0.f,0.f}; acc[a][c] = z; }

  for (int ch = 0; ch < 2; ch++){
    __syncthreads();
    { // stage 4 padded rows x 98 cols x 32 ic, swizzled 16B slots
      const uint4* src = (const uint4*)(inq + (size_t)(b*2 + ch)*PLANE
                                            + (size_t)y0*PX*ICH);
      for (int i = tid; i < 1568; i += 256){
        int r = i / 392, rem = i - r*392;        // 392 uint4 per padded row
        int px = rem >> 2, slot = rem & 3;
        int s = (px & 3) ^ ((px >> 2) & 3);
        *(uint4*)(Bbc + (size_t)r*6272 + (size_t)px*64 + ((slot ^ s)<<4)) = src[i];
      }
    }
    for (int tg = 0; tg < 3; tg++){       // tap row groups (ky = tg)
      __syncthreads();
      { // stage 3 taps x 2 reps x 32 oc (this block's half) x 32 ic, swizzled
        const uint4* srcA = (const uint4*)(apk + (size_t)ch*36864);
        for (int i = tid; i < 768; i += 256){
          int chunk = i >> 7, j = i & 127;       // chunk = tap_r*2+rep, 128 u4/chunk
          int tap_r = chunk >> 1, rep = chunk & 1;
          int oc = j >> 2, slot = j & 3;
          int s = (oc & 3) ^ ((oc >> 2) & 3);
          *(uint4*)(Abc + (size_t)chunk*2048 + (size_t)oc*64 + ((slot ^ s)<<4))
              = srcA[((size_t)((tg*3 + tap_r)*2 + rep))*256 + h*128 + j];
        }
      }
      __syncthreads();
#pragma unroll
      for (int tj = 0; tj < 3; tj++){     // kx = tj
        const int ky = tg, kx = tj;
        bf16x8 Ah[2], Al[2];
#pragma unroll
        for (int mt=0;mt<2;mt++){
          int oc32 = mt*16 + n16;
          int sA = (oc32 & 3) ^ ((oc32 >> 2) & 3);
          Ah[mt] = *(const bf16x8*)(Abc + (size_t)(tj*2 + 0)*2048 + (size_t)oc32*64 + ((q ^ sA)<<4));
          Al[mt] = *(const bf16x8*)(Abc + (size_t)(tj*2 + 1)*2048 + (size_t)oc32*64 + ((q ^ sA)<<4));
        }
        bf16x8 Bf[3];
#pragma unroll
        for (int nt=0;nt<3;nt++){
          int px = wcol + nt*16 + n16 + kx;
          int sB = (px & 3) ^ ((px >> 2) & 3);
          Bf[nt] = *(const bf16x8*)(Bbc + (size_t)(wr + ky)*6272 + (size_t)px*64 + ((q ^ sB)<<4));
        }
#pragma unroll
        for (int nt=0;nt<3;nt++)
#pragma unroll
          for (int mt=0;mt<2;mt++)
            acc[mt][nt] = __builtin_amdgcn_mfma_f32_16x16x32_bf16(Ah[mt], Bf[nt], acc[mt][nt], 0,0,0);
#pragma unroll
        for (int nt=0;nt<3;nt++)
#pragma unroll
          for (int mt=0;mt<2;mt++)
            acc[mt][nt] = __builtin_amdgcn_mfma_f32_16x16x32_bf16(Al[mt], Bf[nt], acc[mt][nt], 0,0,0);
      }
    }
  }

  // ---------------- epilogue ----------------
  if (MODE >= 1){   // yv = -acc (+X at l=7) (+X0 at l=0); coalesced adds (x = lanes)
#pragma unroll
    for (int mt=0;mt<2;mt++)
#pragma unroll
      for (int nt=0;nt<3;nt++){
        const int x = wcol + nt*16 + n16;
#pragma unroll
        for (int r=0;r<4;r++){
          const int oc = h*32 + mt*16 + q*4 + r;
          float v = -acc[mt][nt][r];
          if (Xadd)  v += Xadd[(((size_t)b*64 + oc)*96 + yg)*96 + x];
          if (X0add) v += X0add[((size_t)oc*96 + yg)*96 + x];
          acc[mt][nt][r] = v;
        }
      }
  }
  if (MODE == 2){   // final iter: fused forward scan, fp32 NCHW stores
#pragma unroll
    for (int mt=0;mt<2;mt++)
#pragma unroll
      for (int nt=0;nt<3;nt++){
        const int x = wcol + nt*16 + n16;
#pragma unroll
        for (int r=0;r<4;r++){
          const int oc = h*32 + mt*16 + q*4 + r;
          size_t idx = (((size_t)b*64 + oc)*96 + yg)*96 + x;
          float prev = zb_prev[idx];
          zb_out[idx] = a_i*(b_i*prev + acc[mt][nt][r]);
        }
      }
    return;
  }

  __syncthreads();                        // all waves done with Bb/Ab
  float* T = (float*)smem + w*1584;       // per-wave 48 x 33 fp32 transpose tile
#pragma unroll
  for (int mt2=0; mt2<2; mt2++)
#pragma unroll
    for (int nt=0;nt<3;nt++)
#pragma unroll
      for (int r=0;r<4;r++)
        T[(nt*16 + n16)*33 + mt2*16 + q*4 + r] = acc[mt2][nt][r];
  for (int f = lane; f < 384; f += 64){
    int px = f>>3, c4 = (f&7)*4;
    float vv[4];
#pragma unroll
    for (int k=0;k<4;k++) vv[k] = T[px*33 + c4 + k];
    int x = wcol + px;
    if (MODE == 0){
      float4 val = make_float4(vv[0], vv[1], vv[2], vv[3]);
      *(float4*)(outF + ((((size_t)b*96 + yg)*96 + x)*64 + h*32 + c4)) = val;
    } else {
      size_t off = ((size_t)(b*2 + h)*PY + (yg+1))*(size_t)PX*ICH
                 + (size_t)(x+1)*ICH + c4;
      uint2 pv = *(const uint2*)(yfq_prev + off);
      bf16* ph = (bf16*)&pv;
      union { uint2 v; unsigned short u[4]; } o;
#pragma unroll
      for (int k=0;k<4;k++){
        float yf = a_i*(b_i*(float)ph[k] + vv[k]);
        bf16 hh = (bf16)yf;
        o.u[k] = *(unsigned short*)&hh;
      }
      *(uint2*)(yfq_out + off) = o.v;
    }
  }
}

// ---------------------------------------------------------------------------
extern "C" void kernel_launch(void* const* d_in, const int* in_sizes, int n_in,
                              void* d_out, int out_size, void* d_ws, size_t ws_size,
                              hipStream_t stream) {
  const float* X  = (const float*)d_in[0];
  const float* K  = (const float*)d_in[1];
  const float* X0 = (const float*)d_in[2];

  float* out0  = (float*)d_out;
  float* zbase = out0 + LSTRIDE;

  char* ws = (char*)d_ws;
  float*  statacc = (float*)ws;                         // 1024 f
  float2* st      = (float2*)(ws + 4096);               // 512 f2
  bf16*   apf     = (bf16*)(ws + 8192);
  bf16*   apb     = apf + (size_t)NL*APK_L;
  bf16*   Zq      = apb + (size_t)NL*APK_L;             // 8*PL (doubles as Yfq)
  bf16*   dZq     = Zq + (size_t)NL*PL;                 // PL
  float*  dZf     = (float*)(dZq + PL);                 // LSTRIDE f

  hipMemsetAsync(statacc, 0, 8192, stream);
  hipMemsetAsync(Zq, 0, (size_t)(NL+1)*PL*2, stream);   // zero pads (Zq + dZq)

  pack_weights<<<(NL*9*4096 + 255)/256, 256, 0, stream>>>(K, apf, apb);
  init_yf_t<<<dim3(HC, BB), 256, 0, stream>>>(X, X0, Zq);
  back_scan_q<<<PL/8/256, 256, 0, stream>>>(Zq);

  for (int it = 1; it <= 3; it++){
    for (int l = 0; l < NL; l++){
      conv_mfma<0><<<dim3(48,8,2),256,0,stream>>>(
          Zq + (size_t)l*PL, apf + (size_t)l*APK_L,
          dZf, nullptr, nullptr, nullptr, nullptr, nullptr, nullptr, 0.f, 0.f);
      stats_partial<<<dim3(12,8),256,0,stream>>>(dZf, statacc);
      stat_fin<<<1,512,0,stream>>>(statacc, st);
      norm_cvt<<<LSTRIDE/1024,256,0,stream>>>(dZf, st, dZq);
      float ai = sqrtf((l+1.f)/(l+2.f)), bi = sqrtf((float)l/(float)(l+1));
      if (it < 3)
        conv_mfma<1><<<dim3(48,8,2),256,0,stream>>>(
            dZq, apb + (size_t)l*APK_L,
            nullptr, Zq + (size_t)l*PL, Zq + (size_t)(l>0?l-1:0)*PL,
            nullptr, nullptr,
            (l==NL-1)?X:nullptr, (l==0)?X0:nullptr, ai, bi);
      else
        conv_mfma<2><<<dim3(48,8,2),256,0,stream>>>(
            dZq, apb + (size_t)l*APK_L,
            nullptr, nullptr, nullptr,
            zbase + (size_t)l*LSTRIDE, zbase + (size_t)(l>0?l-1:0)*LSTRIDE,
            (l==NL-1)?X:nullptr, (l==0)?X0:nullptr, ai, bi);
    }
    if (it < 3) back_scan_q<<<PL/8/256,256,0,stream>>>(Zq);
    else        back_scan_final<<<LSTRIDE/256,256,0,stream>>>(zbase, out0);
  }
}